// Round 4
// baseline (513.642 us; speedup 1.0000x reference)
//
#include <hip/hip_runtime.h>
#include <hip/hip_fp16.h>

#define NN 3072
#define DD 256
#define NH 8
#define SPLIT 4
#define KT (NN / SPLIT / 64)   // 12 key-tiles of 64 per split
#define NKT2 (NN / 64)         // 48 global key tiles
#define LN2INV 1.4426950408889634f

typedef _Float16 h16;
typedef __attribute__((ext_vector_type(4))) _Float16 half4;
typedef __attribute__((ext_vector_type(8))) _Float16 half8;
typedef __attribute__((ext_vector_type(4))) float f32x4;

#if __has_builtin(__builtin_amdgcn_exp2f)
#define EXP2(x) __builtin_amdgcn_exp2f(x)
#else
#define EXP2(x) __expf((x) * 0.69314718056f)
#endif

// ------------------------------------------------------------- aug writer ----
__device__ inline void write_aug(int q, float x, float y, float z,
                                 h16* __restrict__ qaug, h16* __restrict__ kaug,
                                 h16* __restrict__ xyzT) {
  float sx = 0.5f * LN2INV * x, sy = 0.5f * LN2INV * y, sz = 0.5f * LN2INV * z;
  h16 shx = (h16)sx, shy = (h16)sy, shz = (h16)sz;
  h16 slx = (h16)(sx - (float)shx), sly = (h16)(sy - (float)shy), slz = (h16)(sz - (float)shz);
  h16 hx = (h16)x, hy = (h16)y, hz = (h16)z;
  h16 lx = (h16)(x - (float)hx), ly = (h16)(y - (float)hy), lz = (h16)(z - (float)hz);
  float n2n = -0.25f * LN2INV * (x * x + y * y + z * z);
  h16 nh = (h16)n2n, nl = (h16)(n2n - (float)nh);
  h16 qa[32], ka[32];
  #pragma unroll
  for (int i = 0; i < 32; ++i) { qa[i] = (h16)0.f; ka[i] = (h16)0.f; }
  qa[0] = shx; qa[1] = shy; qa[2] = shz;       // pairs A d0-2 = hk
  qa[3] = shx; qa[4] = shy; qa[5] = shz;       // pairs A d3-5 = lk
  qa[6] = slx; qa[7] = sly; qa[8] = slz;       // pairs A d6-8 = hk
  qa[9] = (h16)1.f; qa[10] = (h16)1.f;         // pairs key-norm hi/lo
  qa[11] = (h16)n2n;                           // query norm (row-const)
  ka[0] = hx; ka[1] = hy; ka[2] = hz;
  ka[3] = lx; ka[4] = ly; ka[5] = lz;
  ka[6] = hx; ka[7] = hy; ka[8] = hz;
  ka[9] = nh; ka[10] = nl;
  ka[11] = (h16)1.f;
  #pragma unroll
  for (int i = 0; i < 4; ++i) {
    ((half8*)(qaug + (size_t)q * 32))[i] = ((half8*)qa)[i];
    ((half8*)(kaug + (size_t)q * 32))[i] = ((half8*)ka)[i];
  }
  xyzT[q] = (h16)1.f;
  xyzT[1 * NN + q] = hx; xyzT[2 * NN + q] = hy; xyzT[3 * NN + q] = hz;
  xyzT[4 * NN + q] = lx; xyzT[5 * NN + q] = ly; xyzT[6 * NN + q] = lz;
  #pragma unroll
  for (int r = 7; r < 16; ++r) xyzT[(size_t)r * NN + q] = (h16)0.f;
}

// ------------------------------------------------- convert + initial aug -----
__global__ __launch_bounds__(256) void k_convert(
    const float* __restrict__ x, const float* __restrict__ xyz,
    const float* __restrict__ Wq, const float* __restrict__ Wk,
    const float* __restrict__ Wv, const float* __restrict__ Wo,
    h16* __restrict__ xb, h16* __restrict__ wtq, h16* __restrict__ wtk,
    h16* __restrict__ wtv, h16* __restrict__ wto, h16* __restrict__ qaug,
    h16* __restrict__ kaug, h16* __restrict__ xyzT) {
  int t = blockIdx.x * 256 + threadIdx.x;
  const int NX = NN * DD;
  if (t < NX) { xb[t] = (h16)x[t]; return; }
  int u = t - NX;
  if (u < 4 * 65536) {
    int m = u >> 16;
    int e = u & 65535;
    int n = e >> 8, k = e & 255;
    const float* W = (m == 0) ? Wq : (m == 1) ? Wk : (m == 2) ? Wv : Wo;
    h16* wt = (m == 0) ? wtq : (m == 1) ? wtk : (m == 2) ? wtv : wto;
    wt[e] = (h16)W[(k << 8) + n];   // wt[n][k] = W[k][n]
    return;
  }
  int q = u - 4 * 65536;
  if (q < NN) write_aug(q, xyz[q * 3], xyz[q * 3 + 1], xyz[q * 3 + 2], qaug, kaug, xyzT);
}

// ---------------------------------------------------------------- prep dy ----
// dynT2[qt][kt2][lane][slot] = MFMA C-fragment order:
//   query = qt*16 + (lane&15); key = kt2*64 + (slot>>2)*16 + (lane>>4)*4 + (slot&3)
__global__ __launch_bounds__(256) void k_prep(
    const float* __restrict__ dy, const int* __restrict__ dm,
    const int* __restrict__ bim, h16* __restrict__ dynT2) {
  int row = blockIdx.y;                        // query
  int col = blockIdx.x * 256 + threadIdx.x;    // key
  size_t idx = (size_t)row * NN + col;
  bool diag = (row == col);
  bool valid = (dm[idx] != 0 && bim[idx] != 0) || diag;
  float v = valid ? (-LN2INV * (dy[idx] + (diag ? 2.5e-5f : 0.f))) : -43281.f;
  int qt = row >> 4, c = row & 15;
  int kt2 = col >> 6, kk = col & 63;
  int f = kk >> 4, quad = (kk >> 2) & 3, r = kk & 3;
  int lane = (quad << 4) | c;
  dynT2[(((size_t)qt * NKT2 + kt2) << 10) + (lane << 4) + (f << 2) + r] = (h16)v;
}

// ------------------------------------------------------------------- gemm ----
__device__ inline void gemm_body(const h16* __restrict__ A, const h16* __restrict__ Bt,
                                 const float* __restrict__ bias, void* __restrict__ out,
                                 const float* __restrict__ resid, int M, int mode,
                                 float scale, int bx, int by) {
  int lane = threadIdx.x & 63;
  int wave = threadIdx.x >> 6;
  int col = lane & 15, quad = lane >> 4;
  int m0 = bx * 32;
  int n0 = by * 64 + wave * 16;
  f32x4 acc[2];
  acc[0] = (f32x4){0.f, 0.f, 0.f, 0.f};
  acc[1] = (f32x4){0.f, 0.f, 0.f, 0.f};
  #pragma unroll
  for (int kk = 0; kk < DD; kk += 32) {
    half8 b = *(const half8*)(Bt + (size_t)(n0 + col) * DD + kk + quad * 8);
    #pragma unroll
    for (int mr = 0; mr < 2; ++mr) {
      half8 a = *(const half8*)(A + (size_t)(m0 + mr * 16 + col) * DD + kk + quad * 8);
      acc[mr] = __builtin_amdgcn_mfma_f32_16x16x32_f16(a, b, acc[mr], 0, 0, 0);
    }
  }
  float bb = bias[n0 + col];
  #pragma unroll
  for (int mr = 0; mr < 2; ++mr) {
    #pragma unroll
    for (int r = 0; r < 4; ++r) {
      int m = m0 + mr * 16 + quad * 4 + r;
      int n = n0 + col;
      float v = acc[mr][r] + bb;
      if (mode == 0)      ((h16*)out)[(size_t)m * DD + n] = (h16)(v * scale);
      else if (mode == 1) ((h16*)out)[(size_t)n * M + m] = (h16)v;
      else ((float*)out)[(size_t)m * DD + n] = v + resid[(size_t)m * DD + n];
    }
  }
}

__global__ __launch_bounds__(256) void k_gemm(
    const h16* __restrict__ A, const h16* __restrict__ Bt,
    const float* __restrict__ bias, void* __restrict__ out,
    const float* __restrict__ resid, int M, int mode, float scale) {
  gemm_body(A, Bt, bias, out, resid, M, mode, scale, blockIdx.x, blockIdx.y);
}

// QKV fused: z=0 -> qb (scaled), z=1 -> kb, z=2 -> vt (transposed)
__global__ __launch_bounds__(256) void k_gemm3(
    const h16* __restrict__ A, const h16* __restrict__ wtq,
    const h16* __restrict__ wtk, const h16* __restrict__ wtv,
    const float* __restrict__ bq, const float* __restrict__ bk,
    const float* __restrict__ bv, h16* __restrict__ qb, h16* __restrict__ kb,
    h16* __restrict__ vt, float qscale) {
  int z = blockIdx.z;
  const h16* Bt = (z == 0) ? wtq : (z == 1) ? wtk : wtv;
  const float* bias = (z == 0) ? bq : (z == 1) ? bk : bv;
  void* out = (z == 0) ? (void*)qb : (z == 1) ? (void*)kb : (void*)vt;
  gemm_body(A, Bt, bias, out, nullptr, NN, (z == 2) ? 1 : 0,
            (z == 0) ? qscale : 1.f, blockIdx.x, blockIdx.y);
}

// ------------------------------------------------------------- mean shift ----
__device__ inline void ms_load(int qt, int kt2, int lane, int col, int quad, int h,
                               const h16* __restrict__ dynT2,
                               const h16* __restrict__ kaug,
                               const h16* __restrict__ kb,
                               half8 dy[2], half8 ka[4], half8 kf[4]) {
  const h16* d = dynT2 + (((size_t)qt * NKT2 + kt2) << 10) + (lane << 4);
  dy[0] = *(const half8*)d;
  dy[1] = *(const half8*)(d + 8);
  int k0 = kt2 * 64;
  #pragma unroll
  for (int f = 0; f < 4; ++f) {
    ka[f] = *(const half8*)(kaug + (size_t)(k0 + f * 16 + col) * 32 + quad * 8);
    kf[f] = *(const half8*)(kb + (size_t)(k0 + f * 16 + col) * DD + h * 32 + quad * 8);
  }
}

template <int LAST>
__device__ inline void ms_compute(int kt2, const half8 dy[2], const half8 ka[4],
                                  const half8 kf[4], half8 qaf, half8 qf,
                                  const h16* __restrict__ vt,
                                  const h16* __restrict__ xyzT,
                                  h16 (&s_ph)[16][72], int h, int col, int quad,
                                  f32x4& accS, f32x4& fc0, f32x4& fc1) {
  int k0 = kt2 * 64;
  #pragma unroll
  for (int f = 0; f < 4; ++f) {
    f32x4 cc;
    #pragma unroll
    for (int r = 0; r < 4; ++r) cc[r] = (float)dy[f >> 1][(f & 1) * 4 + r];
    f32x4 g = __builtin_amdgcn_mfma_f32_16x16x32_f16(ka[f], qaf, cc, 0, 0, 0);
    f32x4 s = __builtin_amdgcn_mfma_f32_16x16x32_f16(kf[f], qf, g, 0, 0, 0);
    half4 pv;
    #pragma unroll
    for (int r = 0; r < 4; ++r) pv[r] = (h16)EXP2(s[r]);
    *(half4*)&s_ph[col][f * 16 + quad * 4] = pv;
  }
  #pragma unroll
  for (int c = 0; c < 2; ++c) {
    half8 pf = *(const half8*)&s_ph[col][c * 32 + quad * 8];
    half8 xf = *(const half8*)(xyzT + (size_t)col * NN + k0 + c * 32 + quad * 8);
    accS = __builtin_amdgcn_mfma_f32_16x16x32_f16(xf, pf, accS, 0, 0, 0);
    if (LAST) {
      half8 v0 = *(const half8*)(vt + (size_t)(h * 32 + col) * NN + k0 + c * 32 + quad * 8);
      half8 v1 = *(const half8*)(vt + (size_t)(h * 32 + 16 + col) * NN + k0 + c * 32 + quad * 8);
      fc0 = __builtin_amdgcn_mfma_f32_16x16x32_f16(v0, pf, fc0, 0, 0, 0);
      fc1 = __builtin_amdgcn_mfma_f32_16x16x32_f16(v1, pf, fc1, 0, 0, 0);
    }
  }
}

template <int LAST>
__global__ __launch_bounds__(512, 6) void k_msattn(
    const h16* __restrict__ qb, const h16* __restrict__ kb,
    const h16* __restrict__ vt, const h16* __restrict__ dynT2,
    const h16* __restrict__ qaug, const h16* __restrict__ kaug,
    const h16* __restrict__ xyzT, float* __restrict__ den_s,
    float* __restrict__ axh_s, float* __restrict__ axl_s,
    float* __restrict__ numT) {
  __shared__ h16 s_p[NH][16][72];   // per-wave region; zero barriers in kernel
  const int tid = threadIdx.x;
  const int h = tid >> 6;
  const int lane = tid & 63;
  const int col = lane & 15;
  const int quad = lane >> 4;
  const int qt = blockIdx.x;
  const int q0 = qt * 16;
  const int kt2base = blockIdx.y * KT;

  half8 qf  = *(const half8*)(qb + (size_t)(q0 + col) * DD + h * 32 + quad * 8);
  half8 qaf = *(const half8*)(qaug + (size_t)(q0 + col) * 32 + quad * 8);
  f32x4 accS = (f32x4){0.f, 0.f, 0.f, 0.f};
  f32x4 fc0 = (f32x4){0.f, 0.f, 0.f, 0.f};
  f32x4 fc1 = (f32x4){0.f, 0.f, 0.f, 0.f};

  half8 dyA[2], kaA[4], kfA[4];
  half8 dyB[2], kaB[4], kfB[4];
  ms_load(qt, kt2base, lane, col, quad, h, dynT2, kaug, kb, dyA, kaA, kfA);
  #pragma unroll 1
  for (int kt = 0; kt < KT; kt += 2) {
    // prefetch kt+1, compute kt; prefetch kt+2 (may overread 1 tile: ws slack),
    // compute kt+1 — register double-buffer keeps a full tile in flight.
    ms_load(qt, kt2base + kt + 1, lane, col, quad, h, dynT2, kaug, kb, dyB, kaB, kfB);
    ms_compute<LAST>(kt2base + kt, dyA, kaA, kfA, qaf, qf, vt, xyzT,
                     s_p[h], h, col, quad, accS, fc0, fc1);
    ms_load(qt, kt2base + kt + 2, lane, col, quad, h, dynT2, kaug, kb, dyA, kaA, kfA);
    ms_compute<LAST>(kt2base + kt + 1, dyB, kaB, kfB, qaf, qf, vt, xyzT,
                     s_p[h], h, col, quad, accS, fc0, fc1);
  }

  // accS D rows: 0=den, 1-3=num_hi, 4-6=num_lo
  int q = q0 + col;
  size_t sidx = (size_t)(blockIdx.y * NH + h) * NN + q;
  if (quad == 0) {
    den_s[sidx] = accS[0];
    axh_s[sidx * 3 + 0] = accS[1];
    axh_s[sidx * 3 + 1] = accS[2];
    axh_s[sidx * 3 + 2] = accS[3];
  } else if (quad == 1) {
    axl_s[sidx * 3 + 0] = accS[0];
    axl_s[sidx * 3 + 1] = accS[1];
    axl_s[sidx * 3 + 2] = accS[2];
  }
  if (LAST) {
    #pragma unroll
    for (int r = 0; r < 4; ++r) {
      atomicAdd(&numT[(size_t)(h * 32 + quad * 4 + r) * NN + q], fc0[r]);
      atomicAdd(&numT[(size_t)(h * 32 + 16 + quad * 4 + r) * NN + q], fc1[r]);
    }
  }
}

// ---------------------------------------------------------------- combine ----
__global__ __launch_bounds__(256) void k_combine(
    const float* __restrict__ den_s, const float* __restrict__ axh_s,
    const float* __restrict__ axl_s, float* __restrict__ den_tot,
    h16* __restrict__ qaug, h16* __restrict__ kaug, h16* __restrict__ xyzT,
    float* __restrict__ out3) {
  int q = blockIdx.x * 256 + threadIdx.x;
  if (q >= NN) return;
  float X = 0.f, Y = 0.f, Z = 0.f;
  #pragma unroll
  for (int h = 0; h < NH; ++h) {
    float d = 0.f, x = 0.f, y = 0.f, z = 0.f;
    #pragma unroll
    for (int s = 0; s < SPLIT; ++s) {
      size_t idx = (size_t)(s * NH + h) * NN + q;
      d += den_s[idx];
      x += axh_s[idx * 3 + 0] + axl_s[idx * 3 + 0];
      y += axh_s[idx * 3 + 1] + axl_s[idx * 3 + 1];
      z += axh_s[idx * 3 + 2] + axl_s[idx * 3 + 2];
    }
    den_tot[h * NN + q] = d;
    float inv = 0.125f / d;
    X = fmaf(x, inv, X);
    Y = fmaf(y, inv, Y);
    Z = fmaf(z, inv, Z);
  }
  if (out3) {
    out3[q * 3 + 0] = X;
    out3[q * 3 + 1] = Y;
    out3[q * 3 + 2] = Z;
  } else {
    write_aug(q, X, Y, Z, qaug, kaug, xyzT);
  }
}

// ----------------------------------------------------------------- finish ----
__global__ __launch_bounds__(256) void k_finish(
    const float* __restrict__ numT, const float* __restrict__ den_tot,
    h16* __restrict__ featb) {
  __shared__ float tile[32][33];
  int q0 = blockIdx.x * 32, d0 = blockIdx.y * 32;
  int tx = threadIdx.x & 31, ty = threadIdx.x >> 5;   // 32 x 8
  #pragma unroll
  for (int i = 0; i < 4; ++i)
    tile[ty + i * 8][tx] = numT[(size_t)(d0 + ty + i * 8) * NN + q0 + tx];
  __syncthreads();
  int h = d0 >> 5;
  #pragma unroll
  for (int i = 0; i < 4; ++i) {
    int q = q0 + ty + i * 8;
    float inv = 1.f / den_tot[h * NN + q];
    featb[(size_t)q * DD + d0 + tx] = (h16)(tile[tx][ty + i * 8] * inv);
  }
}

// ----------------------------------------------------------------- launch ----
extern "C" void kernel_launch(void* const* d_in, const int* in_sizes, int n_in,
                              void* d_out, int out_size, void* d_ws, size_t ws_size,
                              hipStream_t stream) {
  const float* x   = (const float*)d_in[0];
  const float* xyz = (const float*)d_in[1];
  const float* dy  = (const float*)d_in[2];
  const int* dm    = (const int*)d_in[3];
  const int* bim   = (const int*)d_in[4];
  const float* Wq = (const float*)d_in[5];
  const float* bq = (const float*)d_in[6];
  const float* Wk = (const float*)d_in[7];
  const float* bk = (const float*)d_in[8];
  const float* Wv = (const float*)d_in[9];
  const float* bv = (const float*)d_in[10];
  const float* Wo = (const float*)d_in[11];
  const float* bo = (const float*)d_in[12];

  char* p = (char*)d_ws;
  h16* xb  = (h16*)p; p += (size_t)NN * DD * 2;
  h16* wtq = (h16*)p; p += 256 * 256 * 2;
  h16* wtk = (h16*)p; p += 256 * 256 * 2;
  h16* wtv = (h16*)p; p += 256 * 256 * 2;
  h16* wto = (h16*)p; p += 256 * 256 * 2;
  h16* qb    = (h16*)p; p += (size_t)NN * DD * 2;
  h16* kb    = (h16*)p; p += (size_t)NN * DD * 2;
  h16* vt    = (h16*)p; p += (size_t)NN * DD * 2;
  h16* featb = (h16*)p; p += (size_t)NN * DD * 2;
  h16* dynT2 = (h16*)p; p += (size_t)NN * NN * 2 + 65536;  // +slack: prefetch overread
  h16* qaug  = (h16*)p; p += (size_t)NN * 32 * 2;
  h16* kaug  = (h16*)p; p += (size_t)NN * 32 * 2;
  h16* xyzT  = (h16*)p; p += (size_t)16 * NN * 2;
  float* den_s = (float*)p; p += (size_t)SPLIT * NH * NN * 4;
  float* axh_s = (float*)p; p += (size_t)SPLIT * NH * NN * 3 * 4;
  float* axl_s = (float*)p; p += (size_t)SPLIT * NH * NN * 3 * 4;
  float* den_tot = (float*)p; p += (size_t)NH * NN * 4;
  float* numT = (float*)p; p += (size_t)DD * NN * 4;

  hipMemsetAsync(numT, 0, (size_t)DD * NN * 4, stream);
  k_convert<<<4109, 256, 0, stream>>>(x, xyz, Wq, Wk, Wv, Wo, xb, wtq, wtk, wtv,
                                      wto, qaug, kaug, xyzT);
  k_prep<<<dim3(12, NN), 256, 0, stream>>>(dy, dm, bim, dynT2);
  k_gemm3<<<dim3(96, 4, 3), 256, 0, stream>>>(xb, wtq, wtk, wtv, bq, bk, bv,
                                              qb, kb, vt,
                                              0.17677669529663689f * LN2INV);

  float* xyz_final = (float*)d_out;            // output 0: [3072,3]
  float* out_final = (float*)d_out + NN * 3;   // output 1: [3072,256]

  k_msattn<0><<<dim3(NN / 16, SPLIT), 512, 0, stream>>>(
      qb, kb, vt, dynT2, qaug, kaug, xyzT, den_s, axh_s, axl_s, nullptr);
  k_combine<<<12, 256, 0, stream>>>(den_s, axh_s, axl_s, den_tot,
                                    qaug, kaug, xyzT, nullptr);
  k_msattn<0><<<dim3(NN / 16, SPLIT), 512, 0, stream>>>(
      qb, kb, vt, dynT2, qaug, kaug, xyzT, den_s, axh_s, axl_s, nullptr);
  k_combine<<<12, 256, 0, stream>>>(den_s, axh_s, axl_s, den_tot,
                                    qaug, kaug, xyzT, nullptr);
  k_msattn<1><<<dim3(NN / 16, SPLIT), 512, 0, stream>>>(
      qb, kb, vt, dynT2, qaug, kaug, xyzT, den_s, axh_s, axl_s, numT);
  k_combine<<<12, 256, 0, stream>>>(den_s, axh_s, axl_s, den_tot,
                                    nullptr, nullptr, nullptr, xyz_final);
  k_finish<<<dim3(96, 8), 256, 0, stream>>>(numT, den_tot, featb);
  k_gemm<<<dim3(96, 4), 256, 0, stream>>>(featb, wto, bo, out_final, x, NN, 2, 1.f);
}

// Round 5
// 385.669 us; speedup vs baseline: 1.3318x; 1.3318x over previous
//
#include <hip/hip_runtime.h>
#include <hip/hip_fp16.h>

#define NN 3072
#define DD 256
#define NH 8
#define SPLIT 4
#define KT (NN / SPLIT / 64)   // 12 key-tiles of 64 per split
#define NKT2 (NN / 64)         // 48 global key tiles
#define LN2INV 1.4426950408889634f

typedef _Float16 h16;
typedef __attribute__((ext_vector_type(4))) _Float16 half4;
typedef __attribute__((ext_vector_type(8))) _Float16 half8;
typedef __attribute__((ext_vector_type(4))) float f32x4;

#if __has_builtin(__builtin_amdgcn_exp2f)
#define EXP2(x) __builtin_amdgcn_exp2f(x)
#else
#define EXP2(x) __expf((x) * 0.69314718056f)
#endif

// --------------------------------------------------------- async 16B stage ---
// One wave-wide DMA: lane i copies g[lane*16B] -> l + lane*16B (LDS).
__device__ __forceinline__ void async16(const h16* g, h16* l, int lane) {
#if __has_builtin(__builtin_amdgcn_global_load_lds)
  __builtin_amdgcn_global_load_lds(
      (const __attribute__((address_space(1))) void*)(g + (size_t)lane * 8),
      (__attribute__((address_space(3))) void*)l, 16, 0, 0);
#else
  *(half8*)(l + lane * 8) = *(const half8*)(g + (size_t)lane * 8);
#endif
}

// ------------------------------------------------------------- aug writer ----
// qaug/kaug: 16-dim fp16 aug vectors (geo term via one MFMA, dims 12-15 zero).
// xzT3[kt2][chunk(8)][row(16)][8]: sum-MFMA A tiles {1,xh,yh,zh,xl,yl,zl,0..}.
__device__ inline void write_aug(int q, float x, float y, float z,
                                 h16* __restrict__ qaug, h16* __restrict__ kaug,
                                 h16* __restrict__ xzT3) {
  float sx = 0.5f * LN2INV * x, sy = 0.5f * LN2INV * y, sz = 0.5f * LN2INV * z;
  h16 shx = (h16)sx, shy = (h16)sy, shz = (h16)sz;
  h16 slx = (h16)(sx - (float)shx), sly = (h16)(sy - (float)shy), slz = (h16)(sz - (float)shz);
  h16 hx = (h16)x, hy = (h16)y, hz = (h16)z;
  h16 lx = (h16)(x - (float)hx), ly = (h16)(y - (float)hy), lz = (h16)(z - (float)hz);
  float n2n = -0.25f * LN2INV * (x * x + y * y + z * z);
  h16 nh = (h16)n2n, nl = (h16)(n2n - (float)nh);
  h16 qa[16], ka[16];
  #pragma unroll
  for (int i = 0; i < 16; ++i) { qa[i] = (h16)0.f; ka[i] = (h16)0.f; }
  qa[0] = shx; qa[1] = shy; qa[2] = shz;       // pairs A d0-2 = hk
  qa[3] = shx; qa[4] = shy; qa[5] = shz;       // pairs A d3-5 = lk
  qa[6] = slx; qa[7] = sly; qa[8] = slz;       // pairs A d6-8 = hk
  qa[9] = (h16)1.f; qa[10] = (h16)1.f;         // pairs key-norm hi/lo
  qa[11] = (h16)n2n;                           // query norm (row-const)
  ka[0] = hx; ka[1] = hy; ka[2] = hz;
  ka[3] = lx; ka[4] = ly; ka[5] = lz;
  ka[6] = hx; ka[7] = hy; ka[8] = hz;
  ka[9] = nh; ka[10] = nl;
  ka[11] = (h16)1.f;
  *(half8*)(qaug + (size_t)q * 16) = ((half8*)qa)[0];
  *(half8*)(qaug + (size_t)q * 16 + 8) = ((half8*)qa)[1];
  *(half8*)(kaug + (size_t)q * 16) = ((half8*)ka)[0];
  *(half8*)(kaug + (size_t)q * 16 + 8) = ((half8*)ka)[1];
  int kt2 = q >> 6, kk = q & 63;
  h16* b = xzT3 + ((size_t)kt2 << 10) + (kk >> 3) * 128 + (kk & 7);
  b[0] = (h16)1.f;
  b[8] = hx; b[16] = hy; b[24] = hz;
  b[32] = lx; b[40] = ly; b[48] = lz;
  #pragma unroll
  for (int r = 7; r < 16; ++r) b[r * 8] = (h16)0.f;
}

// ------------------------------------------------- convert + initial aug -----
__global__ __launch_bounds__(256) void k_convert(
    const float* __restrict__ x, const float* __restrict__ xyz,
    const float* __restrict__ Wq, const float* __restrict__ Wk,
    const float* __restrict__ Wv, const float* __restrict__ Wo,
    h16* __restrict__ xb, h16* __restrict__ wtq, h16* __restrict__ wtk,
    h16* __restrict__ wtv, h16* __restrict__ wto, h16* __restrict__ qaug,
    h16* __restrict__ kaug, h16* __restrict__ xzT3) {
  int t = blockIdx.x * 256 + threadIdx.x;
  const int NX = NN * DD;
  if (t < NX) { xb[t] = (h16)x[t]; return; }
  int u = t - NX;
  if (u < 4 * 65536) {
    int m = u >> 16;
    int e = u & 65535;
    int n = e >> 8, k = e & 255;
    const float* W = (m == 0) ? Wq : (m == 1) ? Wk : (m == 2) ? Wv : Wo;
    h16* wt = (m == 0) ? wtq : (m == 1) ? wtk : (m == 2) ? wtv : wto;
    wt[e] = (h16)W[(k << 8) + n];   // wt[n][k] = W[k][n]
    return;
  }
  int q = u - 4 * 65536;
  if (q < NN) write_aug(q, xyz[q * 3], xyz[q * 3 + 1], xyz[q * 3 + 2], qaug, kaug, xzT3);
}

// ---------------------------------------------------------------- prep dy ----
// dynT3[qt][kt2][chunk(2)][lane(64)][8]: staged-linear MFMA C-fragment tiles.
// chunk = f>>1, slot j = (f&1)*4 + r; query = qt*16+(lane&15), key = kt2*64
// + f*16 + (lane>>4)*4 + r.
__global__ __launch_bounds__(256) void k_prep(
    const float* __restrict__ dy, const int* __restrict__ dm,
    const int* __restrict__ bim, h16* __restrict__ dynT3) {
  int row = blockIdx.y;                        // query
  int col = blockIdx.x * 256 + threadIdx.x;    // key
  size_t idx = (size_t)row * NN + col;
  bool diag = (row == col);
  bool valid = (dm[idx] != 0 && bim[idx] != 0) || diag;
  float v = valid ? (-LN2INV * (dy[idx] + (diag ? 2.5e-5f : 0.f))) : -43281.f;
  int qt = row >> 4, c = row & 15;
  int kt2 = col >> 6, kk = col & 63;
  int lane = (((kk >> 2) & 3) << 4) | c;
  size_t off = (((size_t)qt * NKT2 + kt2) * 2 + (kk >> 5)) * 512 +
               lane * 8 + ((kk >> 4) & 1) * 4 + (kk & 3);
  dynT3[off] = (h16)v;
}

// ------------------------------------------------------------------- gemm ----
// mode 0: fp16 row-major *scale; mode 1: fp16 [d][token]; mode 2: fp32 +resid;
// mode 3: fp16 per-head contiguous kbh[h][token][32]
__device__ inline void gemm_body(const h16* __restrict__ A, const h16* __restrict__ Bt,
                                 const float* __restrict__ bias, void* __restrict__ out,
                                 const float* __restrict__ resid, int M, int mode,
                                 float scale, int bx, int by) {
  int lane = threadIdx.x & 63;
  int wave = threadIdx.x >> 6;
  int col = lane & 15, quad = lane >> 4;
  int m0 = bx * 32;
  int n0 = by * 64 + wave * 16;
  f32x4 acc[2];
  acc[0] = (f32x4){0.f, 0.f, 0.f, 0.f};
  acc[1] = (f32x4){0.f, 0.f, 0.f, 0.f};
  #pragma unroll
  for (int kk = 0; kk < DD; kk += 32) {
    half8 b = *(const half8*)(Bt + (size_t)(n0 + col) * DD + kk + quad * 8);
    #pragma unroll
    for (int mr = 0; mr < 2; ++mr) {
      half8 a = *(const half8*)(A + (size_t)(m0 + mr * 16 + col) * DD + kk + quad * 8);
      acc[mr] = __builtin_amdgcn_mfma_f32_16x16x32_f16(a, b, acc[mr], 0, 0, 0);
    }
  }
  float bb = bias[n0 + col];
  #pragma unroll
  for (int mr = 0; mr < 2; ++mr) {
    #pragma unroll
    for (int r = 0; r < 4; ++r) {
      int m = m0 + mr * 16 + quad * 4 + r;
      int n = n0 + col;
      float v = acc[mr][r] + bb;
      if (mode == 0)      ((h16*)out)[(size_t)m * DD + n] = (h16)(v * scale);
      else if (mode == 1) ((h16*)out)[(size_t)n * M + m] = (h16)v;
      else if (mode == 3) ((h16*)out)[((size_t)(n >> 5) * NN + m) * 32 + (n & 31)] = (h16)v;
      else ((float*)out)[(size_t)m * DD + n] = v + resid[(size_t)m * DD + n];
    }
  }
}

__global__ __launch_bounds__(256) void k_gemm(
    const h16* __restrict__ A, const h16* __restrict__ Bt,
    const float* __restrict__ bias, void* __restrict__ out,
    const float* __restrict__ resid, int M, int mode, float scale) {
  gemm_body(A, Bt, bias, out, resid, M, mode, scale, blockIdx.x, blockIdx.y);
}

__global__ __launch_bounds__(256) void k_gemm3(
    const h16* __restrict__ A, const h16* __restrict__ wtq,
    const h16* __restrict__ wtk, const h16* __restrict__ wtv,
    const float* __restrict__ bq, const float* __restrict__ bk,
    const float* __restrict__ bv, h16* __restrict__ qb, h16* __restrict__ kbh,
    h16* __restrict__ vt, float qscale) {
  int z = blockIdx.z;
  const h16* Bt = (z == 0) ? wtq : (z == 1) ? wtk : wtv;
  const float* bias = (z == 0) ? bq : (z == 1) ? bk : bv;
  void* out = (z == 0) ? (void*)qb : (z == 1) ? (void*)kbh : (void*)vt;
  int mode = (z == 0) ? 0 : (z == 1) ? 3 : 1;
  gemm_body(A, Bt, bias, out, nullptr, NN, mode, (z == 0) ? qscale : 1.f,
            blockIdx.x, blockIdx.y);
}

// ------------------------------------------------------------- mean shift ----
__device__ __forceinline__ void stage_tile(int h, int lane, int qt, int kt2,
                                           const h16* __restrict__ dynT3,
                                           const h16* __restrict__ kaug,
                                           const h16* __restrict__ xzT3,
                                           h16* bdy, h16* bka, h16* bxz) {
  if (h < 2)
    async16(dynT3 + (((size_t)qt * NKT2 + kt2) << 10) + h * 512, bdy + h * 512, lane);
  else if (h < 4)
    async16(kaug + ((size_t)kt2 << 10) + (h - 2) * 512, bka + (h - 2) * 512, lane);
  else if (h < 6)
    async16(xzT3 + ((size_t)kt2 << 10) + (h - 4) * 512, bxz + (h - 4) * 512, lane);
}

__device__ __forceinline__ void ldkf(const h16* __restrict__ kbh_h, int k0,
                                     int col, int quad, half8 kf[4]) {
  #pragma unroll
  for (int f = 0; f < 4; ++f)
    kf[f] = *(const half8*)(kbh_h + (size_t)(k0 + f * 16 + col) * 32 + quad * 8);
}

template <int LAST>
__device__ __forceinline__ void ms_compute(
    const h16* __restrict__ bdy, const h16* __restrict__ bka,
    const h16* __restrict__ bxz, const half8 kf[4], half8 qaf, half8 qf,
    const h16* __restrict__ vA, const h16* __restrict__ vB,
    h16 (*s_ph)[72], int lane, int col, int quad,
    f32x4& accS, f32x4& fc0, f32x4& fc1) {
  half8 kz = {};
  half8 dv0 = *(const half8*)(bdy + lane * 8);
  half8 dv1 = *(const half8*)(bdy + 512 + lane * 8);
  #pragma unroll
  for (int f = 0; f < 4; ++f) {
    half8 ka = (quad < 2) ? *(const half8*)(bka + (f * 16 + col) * 16 + quad * 8) : kz;
    half8 dv = (f & 2) ? dv1 : dv0;
    f32x4 cc;
    #pragma unroll
    for (int r = 0; r < 4; ++r) cc[r] = (float)dv[(f & 1) * 4 + r];
    f32x4 g = __builtin_amdgcn_mfma_f32_16x16x32_f16(ka, qaf, cc, 0, 0, 0);
    f32x4 s = __builtin_amdgcn_mfma_f32_16x16x32_f16(kf[f], qf, g, 0, 0, 0);
    half4 pv;
    #pragma unroll
    for (int r = 0; r < 4; ++r) pv[r] = (h16)EXP2(s[r]);
    *(half4*)&s_ph[col][f * 16 + quad * 4] = pv;
  }
  #pragma unroll
  for (int c = 0; c < 2; ++c) {
    half8 pf = *(const half8*)&s_ph[col][c * 32 + quad * 8];
    half8 xf = *(const half8*)(bxz + ((c * 4 + quad) * 16 + col) * 8);
    accS = __builtin_amdgcn_mfma_f32_16x16x32_f16(xf, pf, accS, 0, 0, 0);
    if (LAST) {
      half8 v0 = *(const half8*)(vA + c * 32 + quad * 8);
      half8 v1 = *(const half8*)(vB + c * 32 + quad * 8);
      fc0 = __builtin_amdgcn_mfma_f32_16x16x32_f16(v0, pf, fc0, 0, 0, 0);
      fc1 = __builtin_amdgcn_mfma_f32_16x16x32_f16(v1, pf, fc1, 0, 0, 0);
    }
  }
}

template <int LAST>
__global__ __launch_bounds__(512, 4) void k_msattn(
    const h16* __restrict__ qb, const h16* __restrict__ kbh,
    const h16* __restrict__ vt, const h16* __restrict__ dynT3,
    const h16* __restrict__ qaug, const h16* __restrict__ kaug,
    const h16* __restrict__ xzT3, float* __restrict__ den_s,
    float* __restrict__ axh_s, float* __restrict__ axl_s,
    float* __restrict__ numT) {
  __shared__ h16 s_dy[2][1024];
  __shared__ h16 s_ka[2][1024];
  __shared__ h16 s_xz[2][1024];
  __shared__ h16 s_p[NH][16][72];
  const int tid = threadIdx.x;
  const int h = tid >> 6;
  const int lane = tid & 63;
  const int col = lane & 15;
  const int quad = lane >> 4;
  const int qt = blockIdx.x;
  const int q0 = qt * 16;
  const int tb = blockIdx.y * KT;

  half8 kz = {};
  half8 qf = *(const half8*)(qb + (size_t)(q0 + col) * DD + h * 32 + quad * 8);
  half8 qaf = (quad < 2) ? *(const half8*)(qaug + (size_t)(q0 + col) * 16 + quad * 8) : kz;
  const h16* kbh_h = kbh + (size_t)h * NN * 32;
  const h16* vtA = vt + (size_t)(h * 32 + col) * NN;
  const h16* vtB = vt + (size_t)(h * 32 + 16 + col) * NN;
  f32x4 accS = (f32x4){0.f, 0.f, 0.f, 0.f};
  f32x4 fc0 = (f32x4){0.f, 0.f, 0.f, 0.f};
  f32x4 fc1 = (f32x4){0.f, 0.f, 0.f, 0.f};
  half8 kfA[4], kfB[4];

  stage_tile(h, lane, qt, tb, dynT3, kaug, xzT3, s_dy[0], s_ka[0], s_xz[0]);
  ldkf(kbh_h, tb * 64, col, quad, kfA);
  __syncthreads();          // drains async stage + kfA
  #pragma unroll 1
  for (int kt = 0; kt < KT; kt += 2) {
    int t1 = tb + kt + 1;
    stage_tile(h, lane, qt, t1, dynT3, kaug, xzT3, s_dy[1], s_ka[1], s_xz[1]);
    ldkf(kbh_h, t1 * 64, col, quad, kfB);
    ms_compute<LAST>(s_dy[0], s_ka[0], s_xz[0], kfA, qaf, qf,
                     vtA + (tb + kt) * 64, vtB + (tb + kt) * 64,
                     s_p[h], lane, col, quad, accS, fc0, fc1);
    __syncthreads();        // buf1 + kfB now resident
    int t2 = (kt + 2 < KT) ? tb + kt + 2 : t1;
    if (kt + 2 < KT)
      stage_tile(h, lane, qt, t2, dynT3, kaug, xzT3, s_dy[0], s_ka[0], s_xz[0]);
    ldkf(kbh_h, t2 * 64, col, quad, kfA);
    ms_compute<LAST>(s_dy[1], s_ka[1], s_xz[1], kfB, qaf, qf,
                     vtA + t1 * 64, vtB + t1 * 64,
                     s_p[h], lane, col, quad, accS, fc0, fc1);
    __syncthreads();
  }

  // accS D rows: 0=den, 1-3=num_hi, 4-6=num_lo
  int q = q0 + col;
  size_t sidx = (size_t)(blockIdx.y * NH + h) * NN + q;
  if (quad == 0) {
    den_s[sidx] = accS[0];
    axh_s[sidx * 3 + 0] = accS[1];
    axh_s[sidx * 3 + 1] = accS[2];
    axh_s[sidx * 3 + 2] = accS[3];
  } else if (quad == 1) {
    axl_s[sidx * 3 + 0] = accS[0];
    axl_s[sidx * 3 + 1] = accS[1];
    axl_s[sidx * 3 + 2] = accS[2];
  }
  if (LAST) {
    #pragma unroll
    for (int r = 0; r < 4; ++r) {
      atomicAdd(&numT[(size_t)(h * 32 + quad * 4 + r) * NN + q], fc0[r]);
      atomicAdd(&numT[(size_t)(h * 32 + 16 + quad * 4 + r) * NN + q], fc1[r]);
    }
  }
}

// ---------------------------------------------------------------- combine ----
__global__ __launch_bounds__(256) void k_combine(
    const float* __restrict__ den_s, const float* __restrict__ axh_s,
    const float* __restrict__ axl_s, float* __restrict__ den_tot,
    h16* __restrict__ qaug, h16* __restrict__ kaug, h16* __restrict__ xzT3,
    float* __restrict__ out3) {
  int q = blockIdx.x * 256 + threadIdx.x;
  if (q >= NN) return;
  float X = 0.f, Y = 0.f, Z = 0.f;
  #pragma unroll
  for (int h = 0; h < NH; ++h) {
    float d = 0.f, x = 0.f, y = 0.f, z = 0.f;
    #pragma unroll
    for (int s = 0; s < SPLIT; ++s) {
      size_t idx = (size_t)(s * NH + h) * NN + q;
      d += den_s[idx];
      x += axh_s[idx * 3 + 0] + axl_s[idx * 3 + 0];
      y += axh_s[idx * 3 + 1] + axl_s[idx * 3 + 1];
      z += axh_s[idx * 3 + 2] + axl_s[idx * 3 + 2];
    }
    den_tot[h * NN + q] = d;
    float inv = 0.125f / d;
    X = fmaf(x, inv, X);
    Y = fmaf(y, inv, Y);
    Z = fmaf(z, inv, Z);
  }
  if (out3) {
    out3[q * 3 + 0] = X;
    out3[q * 3 + 1] = Y;
    out3[q * 3 + 2] = Z;
  } else {
    write_aug(q, X, Y, Z, qaug, kaug, xzT3);
  }
}

// ----------------------------------------------------------------- finish ----
__global__ __launch_bounds__(256) void k_finish(
    const float* __restrict__ numT, const float* __restrict__ den_tot,
    h16* __restrict__ featb) {
  __shared__ float tile[32][33];
  int q0 = blockIdx.x * 32, d0 = blockIdx.y * 32;
  int tx = threadIdx.x & 31, ty = threadIdx.x >> 5;   // 32 x 8
  #pragma unroll
  for (int i = 0; i < 4; ++i)
    tile[ty + i * 8][tx] = numT[(size_t)(d0 + ty + i * 8) * NN + q0 + tx];
  __syncthreads();
  int h = d0 >> 5;
  #pragma unroll
  for (int i = 0; i < 4; ++i) {
    int q = q0 + ty + i * 8;
    float inv = 1.f / den_tot[h * NN + q];
    featb[(size_t)q * DD + d0 + tx] = (h16)(tile[tx][ty + i * 8] * inv);
  }
}

// ----------------------------------------------------------------- launch ----
extern "C" void kernel_launch(void* const* d_in, const int* in_sizes, int n_in,
                              void* d_out, int out_size, void* d_ws, size_t ws_size,
                              hipStream_t stream) {
  const float* x   = (const float*)d_in[0];
  const float* xyz = (const float*)d_in[1];
  const float* dy  = (const float*)d_in[2];
  const int* dm    = (const int*)d_in[3];
  const int* bim   = (const int*)d_in[4];
  const float* Wq = (const float*)d_in[5];
  const float* bq = (const float*)d_in[6];
  const float* Wk = (const float*)d_in[7];
  const float* bk = (const float*)d_in[8];
  const float* Wv = (const float*)d_in[9];
  const float* bv = (const float*)d_in[10];
  const float* Wo = (const float*)d_in[11];
  const float* bo = (const float*)d_in[12];

  char* p = (char*)d_ws;
  h16* xb  = (h16*)p; p += (size_t)NN * DD * 2;
  h16* wtq = (h16*)p; p += 256 * 256 * 2;
  h16* wtk = (h16*)p; p += 256 * 256 * 2;
  h16* wtv = (h16*)p; p += 256 * 256 * 2;
  h16* wto = (h16*)p; p += 256 * 256 * 2;
  h16* qb    = (h16*)p; p += (size_t)NN * DD * 2;
  h16* kbh   = (h16*)p; p += (size_t)NN * DD * 2;
  h16* vt    = (h16*)p; p += (size_t)NN * DD * 2;
  h16* featb = (h16*)p; p += (size_t)NN * DD * 2;
  h16* dynT3 = (h16*)p; p += (size_t)NN * NN * 2;
  h16* qaug  = (h16*)p; p += (size_t)NN * 16 * 2;
  h16* kaug  = (h16*)p; p += (size_t)NN * 16 * 2;
  h16* xzT3  = (h16*)p; p += (size_t)NKT2 * 1024 * 2;
  float* den_s = (float*)p; p += (size_t)SPLIT * NH * NN * 4;
  float* axh_s = (float*)p; p += (size_t)SPLIT * NH * NN * 3 * 4;
  float* axl_s = (float*)p; p += (size_t)SPLIT * NH * NN * 3 * 4;
  float* den_tot = (float*)p; p += (size_t)NH * NN * 4;
  float* numT = (float*)p; p += (size_t)DD * NN * 4;

  hipMemsetAsync(numT, 0, (size_t)DD * NN * 4, stream);
  k_convert<<<4108, 256, 0, stream>>>(x, xyz, Wq, Wk, Wv, Wo, xb, wtq, wtk, wtv,
                                      wto, qaug, kaug, xzT3);
  k_prep<<<dim3(12, NN), 256, 0, stream>>>(dy, dm, bim, dynT3);
  k_gemm3<<<dim3(96, 4, 3), 256, 0, stream>>>(xb, wtq, wtk, wtv, bq, bk, bv,
                                              qb, kbh, vt,
                                              0.17677669529663689f * LN2INV);

  float* xyz_final = (float*)d_out;            // output 0: [3072,3]
  float* out_final = (float*)d_out + NN * 3;   // output 1: [3072,256]

  k_msattn<0><<<dim3(NN / 16, SPLIT), 512, 0, stream>>>(
      qb, kbh, vt, dynT3, qaug, kaug, xzT3, den_s, axh_s, axl_s, nullptr);
  k_combine<<<12, 256, 0, stream>>>(den_s, axh_s, axl_s, den_tot,
                                    qaug, kaug, xzT3, nullptr);
  k_msattn<0><<<dim3(NN / 16, SPLIT), 512, 0, stream>>>(
      qb, kbh, vt, dynT3, qaug, kaug, xzT3, den_s, axh_s, axl_s, nullptr);
  k_combine<<<12, 256, 0, stream>>>(den_s, axh_s, axl_s, den_tot,
                                    qaug, kaug, xzT3, nullptr);
  k_msattn<1><<<dim3(NN / 16, SPLIT), 512, 0, stream>>>(
      qb, kbh, vt, dynT3, qaug, kaug, xzT3, den_s, axh_s, axl_s, numT);
  k_combine<<<12, 256, 0, stream>>>(den_s, axh_s, axl_s, den_tot,
                                    nullptr, nullptr, nullptr, xyz_final);
  k_finish<<<dim3(96, 8), 256, 0, stream>>>(numT, den_tot, featb);
  k_gemm<<<dim3(96, 4), 256, 0, stream>>>(featb, wto, bo, out_final, x, NN, 2, 1.f);
}